// Round 4
// baseline (648.444 us; speedup 1.0000x reference)
//
#include <hip/hip_runtime.h>
#include <hip/hip_bf16.h>
#include <math.h>

typedef __bf16 bf16;
typedef __bf16 bf16x8 __attribute__((ext_vector_type(8)));
typedef float f32x4 __attribute__((ext_vector_type(4)));

// Dims derived at runtime. Inputs f32, outputs f32.
// Outputs: out(B,T,H), logits(B,L,V), tt(B,T,C1), pol(B,T,C2), pooled(B,H).
// GEMM1: 128x256 tile, BK=64, XOR-swizzled LDS, fused gelu*wv epilogue.
// GEMM2: 128x128 tile, ZS=1, double-buffered prefetch (stage next -> compute cur
//        -> one barrier), direct out write seeded with wb2 (no partials/atomics).

__device__ __forceinline__ float wsum(float v) {
#pragma unroll
  for (int off = 32; off; off >>= 1) v += __shfl_xor(v, off, 64);
  return v;
}

__device__ __forceinline__ void g2l16(const bf16* g, bf16* l) {
  __builtin_amdgcn_global_load_lds(
      (__attribute__((address_space(1))) void*)g,
      (__attribute__((address_space(3))) void*)l, 16, 0, 0);
}

__device__ __forceinline__ bf16x8 pack8(float4 a, float4 b) {
  bf16x8 r;
  r[0] = (bf16)a.x; r[1] = (bf16)a.y; r[2] = (bf16)a.z; r[3] = (bf16)a.w;
  r[4] = (bf16)b.x; r[5] = (bf16)b.y; r[6] = (bf16)b.z; r[7] = (bf16)b.w;
  return r;
}

// 0.5*x*(1+erf(x/sqrt2)); A&S 7.1.26 (|err|<=1.5e-7), branch-free.
__device__ __forceinline__ float gelu_fast(float x) {
  float s = __builtin_fabsf(x) * 0.70710678118654752f;
  float t = __builtin_amdgcn_rcpf(__builtin_fmaf(0.3275911f, s, 1.0f));
  float p = __builtin_fmaf(t, 1.061405429f, -1.453152027f);
  p = __builtin_fmaf(t, p, 1.421413741f);
  p = __builtin_fmaf(t, p, -0.284496736f);
  p = __builtin_fmaf(t, p, 0.254829592f);
  float e = exp2f(s * s * -1.4426950408889634f);
  float erf_abs = __builtin_fmaf(-p * t, e, 1.0f);
  return __builtin_fmaf(0.5f * __builtin_fabsf(x), erf_abs, 0.5f * x);
}

// ---------- fused: feats + tt/pol outputs + xbE build (ONE x pass) ----------
template <int DCT>
__global__ void k_front_t(const float* __restrict__ x,
                          const float* __restrict__ Wtt, const float* __restrict__ btt,
                          const float* __restrict__ Wpol, const float* __restrict__ bpol,
                          float* __restrict__ out_tt, float* __restrict__ out_pol,
                          float* __restrict__ feats, bf16* __restrict__ xbE,
                          int H, int KE, long BT, int C1, int C2) {
  int wave = threadIdx.x >> 6, lane = threadIdx.x & 63;
  long m = (long)blockIdx.x * 4 + wave;
  if (m >= BT) return;
  const float* xp = x + m * H;
  bf16* dp = xbE + m * KE;
  const float* wp[DCT];
#pragma unroll
  for (int c = 0; c < DCT; c++)
    wp[c] = (c < C1) ? (Wtt + (size_t)c * H) : (Wpol + (size_t)(c - C1) * H);
  float acc[DCT];
#pragma unroll
  for (int c = 0; c < DCT; c++) acc[c] = 0.f;
  for (int e = lane * 8; e + 8 <= H; e += 512) {
    float4 a = *(const float4*)(xp + e);
    float4 b = *(const float4*)(xp + e + 4);
    *(bf16x8*)(dp + e) = pack8(a, b);
#pragma unroll
    for (int c = 0; c < DCT; c++) {
      float4 wa = *(const float4*)(wp[c] + e);
      float4 wb = *(const float4*)(wp[c] + e + 4);
      acc[c] += a.x * wa.x + a.y * wa.y + a.z * wa.z + a.w * wa.w +
                b.x * wb.x + b.y * wb.y + b.z * wb.z + b.w * wb.w;
    }
  }
#pragma unroll
  for (int c = 0; c < DCT; c++) acc[c] = wsum(acc[c]);
  // lane c (c<DCT) owns concept c
  float fv = 0.f;
#pragma unroll
  for (int c = 0; c < DCT; c++) fv = (lane == c) ? acc[c] : fv;
  if (lane < DCT) {
    fv += (lane < C1) ? btt[lane] : bpol[lane - C1];
    if (lane < C1) out_tt[m * C1 + lane] = fv;
    else           out_pol[m * C2 + (lane - C1)] = fv;
    feats[m * DCT + lane] = fv;
  }
  int pad = KE - H;
  if (lane < pad) dp[H + lane] = (lane < DCT) ? (bf16)fv : (bf16)0.f;
}

// generic fallback pieces (runtime DC) — correctness path only
__global__ void k_feats_g(const float* __restrict__ x,
                          const float* __restrict__ Wtt, const float* __restrict__ btt,
                          const float* __restrict__ Wpol, const float* __restrict__ bpol,
                          float* __restrict__ out_tt, float* __restrict__ out_pol,
                          float* __restrict__ feats,
                          int H, int T, int BT, int C1, int C2) {
  int wave = threadIdx.x >> 6, lane = threadIdx.x & 63;
  int site = blockIdx.x * 4 + wave;
  if (site >= BT) return;
  int DC = C1 + C2;
  const float* xp = x + (size_t)site * H;
  for (int c = 0; c < DC; c++) {
    const float* wr = (c < C1) ? (Wtt + (size_t)c * H) : (Wpol + (size_t)(c - C1) * H);
    float a = 0.f;
    for (int k = lane; k < H; k += 64) a += xp[k] * wr[k];
    a = wsum(a);
    if (lane == 0) {
      float val = a + (c < C1 ? btt[c] : bpol[c - C1]);
      if (c < C1) out_tt[(size_t)site * C1 + c] = val;
      else        out_pol[(size_t)site * C2 + (c - C1)] = val;
      feats[(size_t)site * DC + c] = val;
    }
  }
}

__global__ void k_xext(const float* __restrict__ x, const float* __restrict__ feats,
                       bf16* __restrict__ xbE, int H, int KE, int DC, long BT) {
  int wave = threadIdx.x >> 6, lane = threadIdx.x & 63;
  long m = (long)blockIdx.x * 4 + wave;
  if (m >= BT) return;
  const float* xp = x + m * H;
  bf16* dp = xbE + m * KE;
  for (int e = lane * 8; e + 8 <= H; e += 512) {
    float4 a = *(const float4*)(xp + e);
    float4 b = *(const float4*)(xp + e + 4);
    *(bf16x8*)(dp + e) = pack8(a, b);
  }
  int pad = KE - H;
  if (lane < pad)
    dp[H + lane] = (lane < DC) ? (bf16)feats[m * DC + lane] : (bf16)0.f;
}

// ---------- fused weight prep: W1bE build + W2 bf16 convert ----------
__global__ void k_prep(const float* __restrict__ W1, bf16* __restrict__ W1bE,
                       const float* __restrict__ W2, bf16* __restrict__ W2b,
                       int H, int DIN, int KE, int DC, long N2, int nW1, long nCvtThreads) {
  int wave = threadIdx.x >> 6, lane = threadIdx.x & 63;
  if (blockIdx.x < (unsigned)nW1) {
    long n = (long)blockIdx.x * 4 + wave;
    if (n >= N2) return;
    const float* sp = W1 + n * DIN;
    bf16* dp = W1bE + n * KE;
    for (int e = lane * 8; e + 8 <= H; e += 512) {
      float4 a = *(const float4*)(sp + e);
      float4 b = *(const float4*)(sp + e + 4);
      *(bf16x8*)(dp + e) = pack8(a, b);
    }
    int pad = KE - H;
    if (lane < pad)
      dp[H + lane] = (lane < DC) ? (bf16)sp[H + lane] : (bf16)0.f;
  } else {
    long n = N2 * (long)H;
    for (long i = (long)(blockIdx.x - nW1) * 256 + threadIdx.x; i * 8 < n;
         i += nCvtThreads) {
      long e = i * 8;
      if (e + 8 <= n) {
        float4 a = *(const float4*)(W2 + e);
        float4 b = *(const float4*)(W2 + e + 4);
        *(bf16x8*)(W2b + e) = pack8(a, b);
      } else {
        for (long j = e; j < n; j++) W2b[j] = (bf16)W2[j];
      }
    }
  }
}

// ---------- fused: pooled mean over T + fsum reduction ----------
__global__ void k_stats(const float* __restrict__ x, float* __restrict__ pooled,
                        const float* __restrict__ feats, float* __restrict__ fsum,
                        int H, int T, int tsplit, int DC, int BDC, int poolBlocks) {
  int wave = threadIdx.x >> 6, lane = threadIdx.x & 63;
  if (blockIdx.x < (unsigned)poolBlocks) {
    int hBlocks = (H + 255) / 256;
    int bs = blockIdx.x / tsplit, ts = blockIdx.x % tsplit;
    int b = bs / hBlocks;
    int h = (bs % hBlocks) * 256 + threadIdx.x;
    if (h >= H) return;
    int tlo = (int)(((long)T * ts) / tsplit), thi = (int)(((long)T * (ts + 1)) / tsplit);
    const float* p = x + (size_t)b * T * H + h;
    float s = 0.f;
    for (int t = tlo; t < thi; t++) s += p[(size_t)t * H];
    atomicAdd(&pooled[(size_t)b * H + h], s / (float)T);
  } else {
    int r = (blockIdx.x - poolBlocks) * 4 + wave;
    if (r >= BDC) return;
    int b = r / DC, c = r % DC;
    const float* p = feats + ((size_t)b * T) * DC + c;
    float a = 0.f;
    for (int t = lane; t < T; t += 64) a += p[(size_t)t * DC];
    a = wsum(a);
    if (lane == 0) fsum[r] = a / (float)T;
  }
}

// ---------- context -> h0 ----------
__global__ void k_ctx_h0(const float* __restrict__ Wc2h, const float* __restrict__ bc2h,
                         const float* __restrict__ pooled, const float* __restrict__ fmean,
                         float* __restrict__ h0, float* __restrict__ out_pool,
                         int H, int DIN, int B, int DC) {
  int wave = threadIdx.x >> 6, lane = threadIdx.x & 63;
  int r = blockIdx.x * 4 + wave;
  if (r >= B * H) return;
  int b = r / H, j = r % H;
  const float* wrow = Wc2h + (size_t)j * DIN;
  float a = 0.f;
  for (int k = lane; k < DIN; k += 64) {
    float cv = (k < H) ? pooled[(size_t)b * H + k] : fmean[b * DC + (k - H)];
    a += cv * wrow[k];
  }
  a = wsum(a);
  if (lane == 0) {
    h0[r] = a + bc2h[j];
    out_pool[r] = pooled[r];
  }
}

// ---------- one GRU step ----------
__global__ void k_gru(const float* __restrict__ hin, const float* __restrict__ Whh,
                      const float* __restrict__ bih, const float* __restrict__ bhh,
                      float* __restrict__ hout, float* __restrict__ hsl,
                      int H, int B) {
  int wave = threadIdx.x >> 6, lane = threadIdx.x & 63;
  int r = blockIdx.x * 4 + wave;
  if (r >= B * H) return;
  int b = r / H, j = r % H;
  const float* h = hin + (size_t)b * H;
  const float* w0 = Whh + (size_t)j * H;
  const float* w1 = Whh + (size_t)(H + j) * H;
  const float* w2 = Whh + (size_t)(2 * H + j) * H;
  float ar = 0, az = 0, an = 0;
  for (int k = lane; k < H; k += 64) {
    float hv = h[k];
    ar += hv * w0[k];
    az += hv * w1[k];
    an += hv * w2[k];
  }
  ar = wsum(ar); az = wsum(az); an = wsum(an);
  if (lane == 0) {
    float ghr = ar + bhh[j];
    float ghz = az + bhh[H + j];
    float ghn = an + bhh[2 * H + j];
    float rg = 1.f / (1.f + expf(-(bih[j] + ghr)));
    float zg = 1.f / (1.f + expf(-(bih[H + j] + ghz)));
    float ng = tanhf(bih[2 * H + j] + rg * ghn);
    float hn = (1.f - zg) * ng + zg * h[j];
    hout[r] = hn;
    hsl[r] = hn;
  }
}

// ---------- program logits ----------
__global__ void k_logits(const float* __restrict__ hs, const float* __restrict__ Wproj,
                         const float* __restrict__ bproj, float* __restrict__ logits,
                         float* __restrict__ out_log, int H, int B, int L, int V) {
  int wave = threadIdx.x >> 6, lane = threadIdx.x & 63;
  int r = blockIdx.x * 4 + wave;
  if (r >= B * L * V) return;
  int b = r / (L * V), rem = r % (L * V), l = rem / V, u = rem % V;
  const float* h = hs + ((size_t)l * B + b) * H;
  const float* w = Wproj + (size_t)u * H;
  float a = 0.f;
  for (int k = lane; k < H; k += 64) a += h[k] * w[k];
  a = wsum(a);
  if (lane == 0) {
    a += bproj[u];
    int idx = (b * L + l) * V + u;
    logits[idx] = a;
    out_log[idx] = a;
  }
}

// ---------- w[b,v] = mean_l softmax(logits);  wb2[b,o] = sum_v w*b2 ----------
__global__ void k_wmix(const float* __restrict__ logits, const float* __restrict__ b2,
                       float* __restrict__ wv, float* __restrict__ wb2,
                       int B, int L, int V, int H) {
  __shared__ float sm[2048];
  __shared__ float wsh[512];
  int t = threadIdx.x;
  if (t < B * L) {
    const float* lg = logits + t * V;
    float mx = lg[0];
    for (int u = 1; u < V; u++) mx = fmaxf(mx, lg[u]);
    float s = 0.f;
    for (int u = 0; u < V; u++) s += expf(lg[u] - mx);
    for (int u = 0; u < V; u++) sm[t * V + u] = expf(lg[u] - mx) / s;
  }
  __syncthreads();
  if (t < B * V) {
    int b = t / V, u = t % V;
    float a = 0.f;
    for (int l = 0; l < L; l++) a += sm[(b * L + l) * V + u];
    a /= (float)L;
    wsh[t] = a;
    wv[t] = a;
  }
  __syncthreads();
  for (int idx = t; idx < B * H; idx += 256) {
    int b = idx / H, o = idx % H;
    float a = 0.f;
    for (int u = 0; u < V; u++) a += wsh[b * V + u] * b2[(size_t)u * H + o];
    wb2[idx] = a;
  }
}

// ---------- MFMA GEMM1: hmid = wv * gelu(xbE·W1bE^T + b1) (128x256, BK=64) ----------
__global__ __launch_bounds__(256) void gemm1_mfma(
    const bf16* __restrict__ A, const bf16* __restrict__ Bb, bf16* __restrict__ hmid,
    const float* __restrict__ b1, const float* __restrict__ wv,
    int rows, long moff, int KE, int H, int N, int T, int V) {
  __shared__ __align__(16) bf16 As[128 * 64];
  __shared__ __align__(16) bf16 Bs[256 * 64];
  const int wave = threadIdx.x >> 6, lane = threadIdx.x & 63;
  // XCD remap: xcd = f&7 owns n-cols [xcd*4, xcd*4+4) -> B panels L2-resident.
  int bx = blockIdx.x, by = blockIdx.y;
  if (gridDim.x == 32) {
    int f = by * 32 + bx;
    int xcd = f & 7, q = f >> 3;
    bx = xcd * 4 + (q & 3);
    by = q >> 2;
  }
  const int m0 = by * 128, n0 = bx * 256;
  const int mw = (wave >> 1) * 64, nw = (wave & 1) * 128;
  const int rr = lane >> 3;
  const int srcOff = ((lane & 7) ^ rr) << 3;
  const int rA = lane & 15, q4 = lane >> 4;
  f32x4 acc[4][8];
#pragma unroll
  for (int i = 0; i < 4; i++)
#pragma unroll
    for (int j = 0; j < 8; j++) acc[i][j] = (f32x4){0.f, 0.f, 0.f, 0.f};

  int arow[4], brow[8];
#pragma unroll
  for (int t = 0; t < 4; ++t) {
    int r = (wave * 4 + t) * 8 + rr;
    arow[t] = (m0 + r < rows) ? (m0 + r) : (rows - 1);
  }
#pragma unroll
  for (int t = 0; t < 8; ++t) {
    int r = (wave * 8 + t) * 8 + rr;
    brow[t] = (n0 + r < N) ? (n0 + r) : (N - 1);
  }

  for (int k0 = 0; k0 < KE; k0 += 64) {
    __syncthreads();
#pragma unroll
    for (int t = 0; t < 4; ++t)
      g2l16(A + (size_t)arow[t] * KE + k0 + srcOff, &As[(wave * 4 + t) * 512]);
#pragma unroll
    for (int t = 0; t < 8; ++t)
      g2l16(Bb + (size_t)brow[t] * KE + k0 + srcOff, &Bs[(wave * 8 + t) * 512]);
    __syncthreads();
#pragma unroll
    for (int kk = 0; kk < 2; ++kk) {
      bf16x8 af[4];
#pragma unroll
      for (int i = 0; i < 4; i++) {
        int row = mw + i * 16 + rA;
        af[i] = *(const bf16x8*)&As[row * 64 + ((((kk << 2) + q4) ^ (row & 7)) << 3)];
      }
#pragma unroll
      for (int j = 0; j < 8; j++) {
        int row = nw + j * 16 + rA;
        bf16x8 bfr = *(const bf16x8*)&Bs[row * 64 + ((((kk << 2) + q4) ^ (row & 7)) << 3)];
#pragma unroll
        for (int i = 0; i < 4; i++)
          acc[i][j] = __builtin_amdgcn_mfma_f32_16x16x32_bf16(af[i], bfr, acc[i][j], 0, 0, 0);
      }
    }
  }

  int vj[8];
  float b1j[8];
#pragma unroll
  for (int j = 0; j < 8; j++) {
    int n = n0 + nw + j * 16 + rA;
    if (n >= N) n = N - 1;
    vj[j] = n / H;
    b1j[j] = b1[n];
  }
  int bBase = ((T & 127) == 0) ? (int)((moff + m0) / T) : -1;
  float wfac[8];
#pragma unroll
  for (int j = 0; j < 8; j++)
    wfac[j] = (bBase >= 0) ? wv[bBase * V + vj[j]] : 0.f;
#pragma unroll
  for (int i = 0; i < 4; i++) {
#pragma unroll
    for (int r = 0; r < 4; r++) {
      int m = m0 + mw + i * 16 + q4 * 4 + r;
      if (m >= rows) continue;
      long gm = moff + m;
      int bb = (bBase >= 0) ? bBase : (int)(gm / T);
#pragma unroll
      for (int j = 0; j < 8; j++) {
        int n = n0 + nw + j * 16 + rA;
        if (n >= N) continue;
        float val = gelu_fast(acc[i][j][r] + b1j[j]);
        float wf = (bBase >= 0) ? wfac[j] : wv[bb * V + vj[j]];
        hmid[(size_t)m * N + n] = (bf16)(val * wf);
      }
    }
  }
}

// ---------- MFMA GEMM2: out = wb2[b] + hmid·W2b^T (dbuf prefetch, direct write) ----------
__global__ __launch_bounds__(256) void gemm2_mfma(
    const bf16* __restrict__ A, const bf16* __restrict__ W2b,
    const float* __restrict__ wb2, float* __restrict__ outY,
    int rows, long moff, int H, int K, int T) {
  __shared__ __align__(16) bf16 As[2][128 * 64];
  __shared__ __align__(16) bf16 Bs[2][128 * 64];
  const int wave = threadIdx.x >> 6, lane = threadIdx.x & 63;
  // natural order already gives n-block <-> XCD affinity (gridDim.x == 8):
  // consecutive f round-robin XCDs and f&7 == bx, so B-slab (2MB) stays L2-hot.
  const int bx = blockIdx.x, by = blockIdx.y;
  const int m0 = by * 128, n0 = bx * 128;
  const int mw = (wave >> 1) * 64, nw = (wave & 1) * 64;
  const int rr = lane >> 3;
  const int srcOff = ((lane & 7) ^ rr) << 3;
  const int rA = lane & 15, q4 = lane >> 4;
  f32x4 acc[4][4];
#pragma unroll
  for (int i = 0; i < 4; i++)
#pragma unroll
    for (int j = 0; j < 4; j++) acc[i][j] = (f32x4){0.f, 0.f, 0.f, 0.f};

  int arow[4], brow[4];
#pragma unroll
  for (int t = 0; t < 4; ++t) {
    int r = (wave * 4 + t) * 8 + rr;
    arow[t] = (m0 + r < rows) ? (m0 + r) : (rows - 1);
    brow[t] = (n0 + r < H) ? (n0 + r) : (H - 1);
  }

  // stage walker
  int k0s = 0, kvs = 0, khs = 0;
  const int nt = K / 64;
  // prologue: stage tile 0 into buf 0
  {
    const bf16* Bk = W2b + (size_t)kvs * H * H + khs;
#pragma unroll
    for (int t = 0; t < 4; ++t) {
      int c = wave * 4 + t;
      g2l16(A + (size_t)arow[t] * K + k0s + srcOff, &As[0][c * 512]);
      g2l16(Bk + (size_t)brow[t] * H + srcOff, &Bs[0][c * 512]);
    }
    k0s += 64; khs += 64; if (khs >= H) { khs = 0; kvs++; }
  }
  __syncthreads();  // drains vmcnt(0): buf0 ready

  int cur = 0;
  for (int t = 0; t < nt; ++t) {
    if (t + 1 < nt) {  // issue next-tile loads BEFORE computing current
      const bf16* Bk = W2b + (size_t)kvs * H * H + khs;
#pragma unroll
      for (int s = 0; s < 4; ++s) {
        int c = wave * 4 + s;
        g2l16(A + (size_t)arow[s] * K + k0s + srcOff, &As[cur ^ 1][c * 512]);
        g2l16(Bk + (size_t)brow[s] * H + srcOff, &Bs[cur ^ 1][c * 512]);
      }
      k0s += 64; khs += 64; if (khs >= H) { khs = 0; kvs++; }
    }
#pragma unroll
    for (int kk = 0; kk < 2; ++kk) {
      bf16x8 af[4], bfr[4];
#pragma unroll
      for (int i = 0; i < 4; i++) {
        int row = mw + i * 16 + rA;
        af[i] = *(const bf16x8*)&As[cur][row * 64 + ((((kk << 2) + q4) ^ (row & 7)) << 3)];
      }
#pragma unroll
      for (int j = 0; j < 4; j++) {
        int row = nw + j * 16 + rA;
        bfr[j] = *(const bf16x8*)&Bs[cur][row * 64 + ((((kk << 2) + q4) ^ (row & 7)) << 3)];
      }
#pragma unroll
      for (int i = 0; i < 4; i++)
#pragma unroll
        for (int j = 0; j < 4; j++)
          acc[i][j] = __builtin_amdgcn_mfma_f32_16x16x32_bf16(af[i], bfr[j], acc[i][j], 0, 0, 0);
    }
    __syncthreads();  // compiler emits vmcnt(0) drain: prefetched buf ready
    cur ^= 1;
  }

  int bBase = ((T & 127) == 0) ? (int)((moff + m0) / T) : -1;
#pragma unroll
  for (int i = 0; i < 4; i++) {
#pragma unroll
    for (int r = 0; r < 4; r++) {
      int m = m0 + mw + i * 16 + q4 * 4 + r;
      if (m >= rows) continue;
      long gm = moff + m;
      int bb = (bBase >= 0) ? bBase : (int)(gm / T);
      const float* wrow = wb2 + (size_t)bb * H;
#pragma unroll
      for (int j = 0; j < 4; j++) {
        int n = n0 + nw + j * 16 + rA;
        if (n >= H) continue;
        outY[(size_t)gm * H + n] = acc[i][j][r] + wrow[n];
      }
    }
  }
}

extern "C" void kernel_launch(void* const* d_in, const int* in_sizes, int n_in,
                              void* d_out, int out_size, void* d_ws, size_t ws_size,
                              hipStream_t stream) {
  const float* x      = (const float*)d_in[0];
  const float* W_tt   = (const float*)d_in[1];
  const float* b_tt   = (const float*)d_in[2];
  const float* W_pol  = (const float*)d_in[3];
  const float* b_pol  = (const float*)d_in[4];
  const float* W_c2h  = (const float*)d_in[5];
  const float* b_c2h  = (const float*)d_in[6];
  const float* W_hh   = (const float*)d_in[8];
  const float* b_ih   = (const float*)d_in[9];
  const float* b_hh   = (const float*)d_in[10];
  const float* W_proj = (const float*)d_in[11];
  const float* b_proj = (const float*)d_in[12];
  const float* W1     = (const float*)d_in[13];
  const float* b1     = (const float*)d_in[14];
  const float* W2     = (const float*)d_in[15];
  const float* b2     = (const float*)d_in[16];
  float* out = (float*)d_out;
  char* ws = (char*)d_ws;

  const int C1 = in_sizes[2];
  const int C2 = in_sizes[4];
  const int H  = in_sizes[1] / C1;
  const int DC = C1 + C2;
  const int DIN = H + DC;
  const int V  = in_sizes[12];
  const long BT = (long)in_sizes[0] / H;
  long R = (long)out_size - BT * (long)(H + DC);
  int B = 0, L = 0;
  for (int Lc = 1; Lc <= 32; ++Lc) {
    long den = (long)Lc * V + H;
    if (R % den == 0) {
      long Bc = R / den;
      if (Bc >= 1 && BT % Bc == 0) {
        if (B == 0 || Lc == 4) { B = (int)Bc; L = Lc; }
        if (Lc == 4) break;
      }
    }
  }
  if (B == 0) { B = 8; L = 4; }
  const int T = (int)(BT / B);
  const long N2 = (long)V * H;
  const int KE = H + 64;          // BK=64-aligned K-extension (zero padded)

  size_t o = 0;
  auto alloc = [&](size_t bytes) { size_t r = o; o = (o + bytes + 255) & ~(size_t)255; return r; };
  float* feats  = (float*)(ws + alloc((size_t)BT * DC * 4));
  size_t off_pooled = alloc((size_t)B * H * 4);
  float* pooled = (float*)(ws + off_pooled);
  float* fsum   = (float*)(ws + alloc((size_t)B * DC * 4));
  float* hbuf   = (float*)(ws + alloc((size_t)2 * B * H * 4));
  float* hs     = (float*)(ws + alloc((size_t)L * B * H * 4));
  float* logits = (float*)(ws + alloc((size_t)B * L * V * 4));
  float* wv     = (float*)(ws + alloc((size_t)B * V * 4));
  float* wb2    = (float*)(ws + alloc((size_t)B * H * 4));
  bf16* xbE  = (bf16*)(ws + alloc((size_t)BT * KE * 2));
  bf16* W1bE = (bf16*)(ws + alloc((size_t)N2 * KE * 2));
  bf16* W2b  = (bf16*)(ws + alloc((size_t)N2 * H * 2));
  size_t off_hmid = alloc(0);
  long avail = (long)ws_size - (long)off_hmid;
  long Mc = ((avail / (N2 * 2)) / 128) * 128;
  long bt128 = ((BT + 127) / 128) * 128;
  if (Mc > bt128) Mc = bt128;
  if (Mc < 128) Mc = 128;
  bf16* hmid = (bf16*)(ws + off_hmid);

  float* out_y    = out;
  float* out_log  = out_y + (size_t)BT * H;
  float* out_tt   = out_log + (size_t)B * L * V;
  float* out_pol  = out_tt + (size_t)BT * C1;
  float* out_pool = out_pol + (size_t)BT * C2;

  hipMemsetAsync(ws + off_pooled, 0, (size_t)B * H * 4, stream);

  // weight prep (W1bE + W2b) in one kernel
  int nW1 = (int)((N2 + 3) / 4);
  int nCvt = 1024;
  k_prep<<<nW1 + nCvt, 256, 0, stream>>>(W1, W1bE, W2, W2b, H, DIN, KE, DC, N2,
                                         nW1, (long)nCvt * 256);
  // front: feats/tt/pol + xbE in one x pass
  if (DC == 8 && (H & 1023) == 0) {
    k_front_t<8><<<(int)((BT + 3) / 4), 256, 0, stream>>>(x, W_tt, b_tt, W_pol, b_pol,
                                                          out_tt, out_pol, feats, xbE,
                                                          H, KE, BT, C1, C2);
  } else {
    k_feats_g<<<(int)((BT + 3) / 4), 256, 0, stream>>>(x, W_tt, b_tt, W_pol, b_pol,
                                                       out_tt, out_pol, feats,
                                                       H, T, (int)BT, C1, C2);
    k_xext<<<(int)((BT + 3) / 4), 256, 0, stream>>>(x, feats, xbE, H, KE, DC, BT);
  }
  // pooled + fsum in one kernel
  int hBlocks = (H + 255) / 256;
  int poolBlocks = B * hBlocks * 8;
  int fsumBlocks = (B * DC + 3) / 4;
  k_stats<<<poolBlocks + fsumBlocks, 256, 0, stream>>>(x, pooled, feats, fsum,
                                                       H, T, 8, DC, B * DC, poolBlocks);
  k_ctx_h0<<<(B * H + 3) / 4, 256, 0, stream>>>(W_c2h, b_c2h, pooled, fsum,
                                                hbuf, out_pool, H, DIN, B, DC);
  float* hA = hbuf;
  float* hB = hbuf + (size_t)B * H;
  for (int l = 0; l < L; ++l) {
    k_gru<<<(B * H + 3) / 4, 256, 0, stream>>>((l & 1) ? hB : hA, W_hh, b_ih, b_hh,
                                               (l & 1) ? hA : hB, hs + (size_t)l * B * H,
                                               H, B);
  }
  k_logits<<<(B * L * V + 3) / 4, 256, 0, stream>>>(hs, W_proj, b_proj, logits,
                                                    out_log, H, B, L, V);
  k_wmix<<<1, 256, 0, stream>>>(logits, b2, wv, wb2, B, L, V, H);

  for (long moff = 0; moff < BT; moff += Mc) {
    int rows = (int)(((BT - moff) < Mc) ? (BT - moff) : Mc);
    dim3 g1((unsigned)((N2 + 255) / 256), (unsigned)((rows + 127) / 128));
    dim3 g2((unsigned)((H + 127) / 128), (unsigned)((rows + 127) / 128));
    gemm1_mfma<<<g1, 256, 0, stream>>>(xbE + (size_t)moff * KE, W1bE, hmid, b1, wv,
                                       rows, moff, KE, H, (int)N2, T, V);
    gemm2_mfma<<<g2, 256, 0, stream>>>(hmid, W2b, wb2, out_y,
                                       rows, moff, H, (int)N2, T);
  }
}

// Round 5
// 454.934 us; speedup vs baseline: 1.4254x; 1.4254x over previous
//
#include <hip/hip_runtime.h>
#include <hip/hip_bf16.h>
#include <math.h>

typedef __bf16 bf16;
typedef __bf16 bf16x8 __attribute__((ext_vector_type(8)));
typedef float f32x4 __attribute__((ext_vector_type(4)));

// Dims derived at runtime. Inputs f32, outputs f32.
// Outputs: out(B,T,H), logits(B,L,V), tt(B,T,C1), pol(B,T,C2), pooled(B,H).
// GEMM1: 128x128 tile, BK=64, XOR-swizzled LDS, fused gelu*wv epilogue.
//   (128x256 tried in R3: acc regs blew unified VGPR file -> 1 block/CU,
//    occupancy 11.7%, 2.4x SLOWER. Keep 128x128: VGPR 64, 3 blocks/CU.)
// GEMM2: 128x128, ZS=4 K-split into f32 partials (no atomics), k_red folds
//   wb2 seed + partial sum. ZS=4 keeps grid at 4 blocks/CU.

__device__ __forceinline__ float wsum(float v) {
#pragma unroll
  for (int off = 32; off; off >>= 1) v += __shfl_xor(v, off, 64);
  return v;
}

__device__ __forceinline__ void g2l16(const bf16* g, bf16* l) {
  __builtin_amdgcn_global_load_lds(
      (__attribute__((address_space(1))) void*)g,
      (__attribute__((address_space(3))) void*)l, 16, 0, 0);
}

__device__ __forceinline__ bf16x8 pack8(float4 a, float4 b) {
  bf16x8 r;
  r[0] = (bf16)a.x; r[1] = (bf16)a.y; r[2] = (bf16)a.z; r[3] = (bf16)a.w;
  r[4] = (bf16)b.x; r[5] = (bf16)b.y; r[6] = (bf16)b.z; r[7] = (bf16)b.w;
  return r;
}

// 0.5*x*(1+erf(x/sqrt2)); A&S 7.1.26 (|err|<=1.5e-7), branch-free.
__device__ __forceinline__ float gelu_fast(float x) {
  float s = __builtin_fabsf(x) * 0.70710678118654752f;
  float t = __builtin_amdgcn_rcpf(__builtin_fmaf(0.3275911f, s, 1.0f));
  float p = __builtin_fmaf(t, 1.061405429f, -1.453152027f);
  p = __builtin_fmaf(t, p, 1.421413741f);
  p = __builtin_fmaf(t, p, -0.284496736f);
  p = __builtin_fmaf(t, p, 0.254829592f);
  float e = exp2f(s * s * -1.4426950408889634f);
  float erf_abs = __builtin_fmaf(-p * t, e, 1.0f);
  return __builtin_fmaf(0.5f * __builtin_fabsf(x), erf_abs, 0.5f * x);
}

// ---------- fused: feats + tt/pol outputs + xbE build (ONE x pass) ----------
template <int DCT>
__global__ void k_front_t(const float* __restrict__ x,
                          const float* __restrict__ Wtt, const float* __restrict__ btt,
                          const float* __restrict__ Wpol, const float* __restrict__ bpol,
                          float* __restrict__ out_tt, float* __restrict__ out_pol,
                          float* __restrict__ feats, bf16* __restrict__ xbE,
                          int H, int KE, long BT, int C1, int C2) {
  int wave = threadIdx.x >> 6, lane = threadIdx.x & 63;
  long m = (long)blockIdx.x * 4 + wave;
  if (m >= BT) return;
  const float* xp = x + m * H;
  bf16* dp = xbE + m * KE;
  const float* wp[DCT];
#pragma unroll
  for (int c = 0; c < DCT; c++)
    wp[c] = (c < C1) ? (Wtt + (size_t)c * H) : (Wpol + (size_t)(c - C1) * H);
  float acc[DCT];
#pragma unroll
  for (int c = 0; c < DCT; c++) acc[c] = 0.f;
  for (int e = lane * 8; e + 8 <= H; e += 512) {
    float4 a = *(const float4*)(xp + e);
    float4 b = *(const float4*)(xp + e + 4);
    *(bf16x8*)(dp + e) = pack8(a, b);
#pragma unroll
    for (int c = 0; c < DCT; c++) {
      float4 wa = *(const float4*)(wp[c] + e);
      float4 wb = *(const float4*)(wp[c] + e + 4);
      acc[c] += a.x * wa.x + a.y * wa.y + a.z * wa.z + a.w * wa.w +
                b.x * wb.x + b.y * wb.y + b.z * wb.z + b.w * wb.w;
    }
  }
#pragma unroll
  for (int c = 0; c < DCT; c++) acc[c] = wsum(acc[c]);
  // lane c (c<DCT) owns concept c
  float fv = 0.f;
#pragma unroll
  for (int c = 0; c < DCT; c++) fv = (lane == c) ? acc[c] : fv;
  if (lane < DCT) {
    fv += (lane < C1) ? btt[lane] : bpol[lane - C1];
    if (lane < C1) out_tt[m * C1 + lane] = fv;
    else           out_pol[m * C2 + (lane - C1)] = fv;
    feats[m * DCT + lane] = fv;
  }
  int pad = KE - H;
  if (lane < pad) dp[H + lane] = (lane < DCT) ? (bf16)fv : (bf16)0.f;
}

// generic fallback pieces (runtime DC) — correctness path only
__global__ void k_feats_g(const float* __restrict__ x,
                          const float* __restrict__ Wtt, const float* __restrict__ btt,
                          const float* __restrict__ Wpol, const float* __restrict__ bpol,
                          float* __restrict__ out_tt, float* __restrict__ out_pol,
                          float* __restrict__ feats,
                          int H, int T, int BT, int C1, int C2) {
  int wave = threadIdx.x >> 6, lane = threadIdx.x & 63;
  int site = blockIdx.x * 4 + wave;
  if (site >= BT) return;
  int DC = C1 + C2;
  const float* xp = x + (size_t)site * H;
  for (int c = 0; c < DC; c++) {
    const float* wr = (c < C1) ? (Wtt + (size_t)c * H) : (Wpol + (size_t)(c - C1) * H);
    float a = 0.f;
    for (int k = lane; k < H; k += 64) a += xp[k] * wr[k];
    a = wsum(a);
    if (lane == 0) {
      float val = a + (c < C1 ? btt[c] : bpol[c - C1]);
      if (c < C1) out_tt[(size_t)site * C1 + c] = val;
      else        out_pol[(size_t)site * C2 + (c - C1)] = val;
      feats[(size_t)site * DC + c] = val;
    }
  }
}

__global__ void k_xext(const float* __restrict__ x, const float* __restrict__ feats,
                       bf16* __restrict__ xbE, int H, int KE, int DC, long BT) {
  int wave = threadIdx.x >> 6, lane = threadIdx.x & 63;
  long m = (long)blockIdx.x * 4 + wave;
  if (m >= BT) return;
  const float* xp = x + m * H;
  bf16* dp = xbE + m * KE;
  for (int e = lane * 8; e + 8 <= H; e += 512) {
    float4 a = *(const float4*)(xp + e);
    float4 b = *(const float4*)(xp + e + 4);
    *(bf16x8*)(dp + e) = pack8(a, b);
  }
  int pad = KE - H;
  if (lane < pad)
    dp[H + lane] = (lane < DC) ? (bf16)feats[m * DC + lane] : (bf16)0.f;
}

// ---------- fused weight prep: W1bE build + W2 bf16 convert ----------
__global__ void k_prep(const float* __restrict__ W1, bf16* __restrict__ W1bE,
                       const float* __restrict__ W2, bf16* __restrict__ W2b,
                       int H, int DIN, int KE, int DC, long N2, int nW1, long nCvtThreads) {
  int wave = threadIdx.x >> 6, lane = threadIdx.x & 63;
  if (blockIdx.x < (unsigned)nW1) {
    long n = (long)blockIdx.x * 4 + wave;
    if (n >= N2) return;
    const float* sp = W1 + n * DIN;
    bf16* dp = W1bE + n * KE;
    for (int e = lane * 8; e + 8 <= H; e += 512) {
      float4 a = *(const float4*)(sp + e);
      float4 b = *(const float4*)(sp + e + 4);
      *(bf16x8*)(dp + e) = pack8(a, b);
    }
    int pad = KE - H;
    if (lane < pad)
      dp[H + lane] = (lane < DC) ? (bf16)sp[H + lane] : (bf16)0.f;
  } else {
    long n = N2 * (long)H;
    for (long i = (long)(blockIdx.x - nW1) * 256 + threadIdx.x; i * 8 < n;
         i += nCvtThreads) {
      long e = i * 8;
      if (e + 8 <= n) {
        float4 a = *(const float4*)(W2 + e);
        float4 b = *(const float4*)(W2 + e + 4);
        *(bf16x8*)(W2b + e) = pack8(a, b);
      } else {
        for (long j = e; j < n; j++) W2b[j] = (bf16)W2[j];
      }
    }
  }
}

// ---------- fused: pooled mean over T + fsum reduction ----------
__global__ void k_stats(const float* __restrict__ x, float* __restrict__ pooled,
                        const float* __restrict__ feats, float* __restrict__ fsum,
                        int H, int T, int tsplit, int DC, int BDC, int poolBlocks) {
  int wave = threadIdx.x >> 6, lane = threadIdx.x & 63;
  if (blockIdx.x < (unsigned)poolBlocks) {
    int hBlocks = (H + 255) / 256;
    int bs = blockIdx.x / tsplit, ts = blockIdx.x % tsplit;
    int b = bs / hBlocks;
    int h = (bs % hBlocks) * 256 + threadIdx.x;
    if (h >= H) return;
    int tlo = (int)(((long)T * ts) / tsplit), thi = (int)(((long)T * (ts + 1)) / tsplit);
    const float* p = x + (size_t)b * T * H + h;
    float s = 0.f;
    for (int t = tlo; t < thi; t++) s += p[(size_t)t * H];
    atomicAdd(&pooled[(size_t)b * H + h], s / (float)T);
  } else {
    int r = (blockIdx.x - poolBlocks) * 4 + wave;
    if (r >= BDC) return;
    int b = r / DC, c = r % DC;
    const float* p = feats + ((size_t)b * T) * DC + c;
    float a = 0.f;
    for (int t = lane; t < T; t += 64) a += p[(size_t)t * DC];
    a = wsum(a);
    if (lane == 0) fsum[r] = a / (float)T;
  }
}

// ---------- context -> h0 ----------
__global__ void k_ctx_h0(const float* __restrict__ Wc2h, const float* __restrict__ bc2h,
                         const float* __restrict__ pooled, const float* __restrict__ fmean,
                         float* __restrict__ h0, float* __restrict__ out_pool,
                         int H, int DIN, int B, int DC) {
  int wave = threadIdx.x >> 6, lane = threadIdx.x & 63;
  int r = blockIdx.x * 4 + wave;
  if (r >= B * H) return;
  int b = r / H, j = r % H;
  const float* wrow = Wc2h + (size_t)j * DIN;
  float a = 0.f;
  for (int k = lane; k < DIN; k += 64) {
    float cv = (k < H) ? pooled[(size_t)b * H + k] : fmean[b * DC + (k - H)];
    a += cv * wrow[k];
  }
  a = wsum(a);
  if (lane == 0) {
    h0[r] = a + bc2h[j];
    out_pool[r] = pooled[r];
  }
}

// ---------- one GRU step ----------
__global__ void k_gru(const float* __restrict__ hin, const float* __restrict__ Whh,
                      const float* __restrict__ bih, const float* __restrict__ bhh,
                      float* __restrict__ hout, float* __restrict__ hsl,
                      int H, int B) {
  int wave = threadIdx.x >> 6, lane = threadIdx.x & 63;
  int r = blockIdx.x * 4 + wave;
  if (r >= B * H) return;
  int b = r / H, j = r % H;
  const float* h = hin + (size_t)b * H;
  const float* w0 = Whh + (size_t)j * H;
  const float* w1 = Whh + (size_t)(H + j) * H;
  const float* w2 = Whh + (size_t)(2 * H + j) * H;
  float ar = 0, az = 0, an = 0;
  for (int k = lane; k < H; k += 64) {
    float hv = h[k];
    ar += hv * w0[k];
    az += hv * w1[k];
    an += hv * w2[k];
  }
  ar = wsum(ar); az = wsum(az); an = wsum(an);
  if (lane == 0) {
    float ghr = ar + bhh[j];
    float ghz = az + bhh[H + j];
    float ghn = an + bhh[2 * H + j];
    float rg = 1.f / (1.f + expf(-(bih[j] + ghr)));
    float zg = 1.f / (1.f + expf(-(bih[H + j] + ghz)));
    float ng = tanhf(bih[2 * H + j] + rg * ghn);
    float hn = (1.f - zg) * ng + zg * h[j];
    hout[r] = hn;
    hsl[r] = hn;
  }
}

// ---------- program logits ----------
__global__ void k_logits(const float* __restrict__ hs, const float* __restrict__ Wproj,
                         const float* __restrict__ bproj, float* __restrict__ logits,
                         float* __restrict__ out_log, int H, int B, int L, int V) {
  int wave = threadIdx.x >> 6, lane = threadIdx.x & 63;
  int r = blockIdx.x * 4 + wave;
  if (r >= B * L * V) return;
  int b = r / (L * V), rem = r % (L * V), l = rem / V, u = rem % V;
  const float* h = hs + ((size_t)l * B + b) * H;
  const float* w = Wproj + (size_t)u * H;
  float a = 0.f;
  for (int k = lane; k < H; k += 64) a += h[k] * w[k];
  a = wsum(a);
  if (lane == 0) {
    a += bproj[u];
    int idx = (b * L + l) * V + u;
    logits[idx] = a;
    out_log[idx] = a;
  }
}

// ---------- w[b,v] = mean_l softmax(logits);  wb2[b,o] = sum_v w*b2 ----------
__global__ void k_wmix(const float* __restrict__ logits, const float* __restrict__ b2,
                       float* __restrict__ wv, float* __restrict__ wb2,
                       int B, int L, int V, int H) {
  __shared__ float sm[2048];
  __shared__ float wsh[512];
  int t = threadIdx.x;
  if (t < B * L) {
    const float* lg = logits + t * V;
    float mx = lg[0];
    for (int u = 1; u < V; u++) mx = fmaxf(mx, lg[u]);
    float s = 0.f;
    for (int u = 0; u < V; u++) s += expf(lg[u] - mx);
    for (int u = 0; u < V; u++) sm[t * V + u] = expf(lg[u] - mx) / s;
  }
  __syncthreads();
  if (t < B * V) {
    int b = t / V, u = t % V;
    float a = 0.f;
    for (int l = 0; l < L; l++) a += sm[(b * L + l) * V + u];
    a /= (float)L;
    wsh[t] = a;
    wv[t] = a;
  }
  __syncthreads();
  for (int idx = t; idx < B * H; idx += 256) {
    int b = idx / H, o = idx % H;
    float a = 0.f;
    for (int u = 0; u < V; u++) a += wsh[b * V + u] * b2[(size_t)u * H + o];
    wb2[idx] = a;
  }
}

// ---------- MFMA GEMM1: hmid = wv * gelu(xbE·W1bE^T + b1)  (BK=64, swizzled) ----------
__global__ __launch_bounds__(256, 2) void gemm1_mfma(
    const bf16* __restrict__ A, const bf16* __restrict__ Bb, bf16* __restrict__ hmid,
    const float* __restrict__ b1, const float* __restrict__ wv,
    int rows, long moff, int KE, int H, int N, int T, int V) {
  __shared__ __align__(16) bf16 As[128 * 64];
  __shared__ __align__(16) bf16 Bs[128 * 64];
  const int wave = threadIdx.x >> 6, lane = threadIdx.x & 63;
  // XCD-chunked remap: XCD k owns n-chunk-column k (B panels L2-resident per XCD).
  int bx = blockIdx.x, by = blockIdx.y;
  if (gridDim.x == 64 && (gridDim.y & 3) == 0) {
    int f = by * 64 + bx;
    int xcd = f & 7, q = f >> 3;
    int cs = q >> 5, t = q & 31;
    bx = xcd * 8 + (t & 7);
    by = cs * 4 + (t >> 3);
  }
  const int m0 = by * 128, n0 = bx * 128;
  const int mw = (wave >> 1) * 64, nw = (wave & 1) * 64;
  const int rr = lane >> 3;                       // stage row in 8-row chunk
  const int srcOff = ((lane & 7) ^ rr) << 3;      // swizzled source slot (elems)
  const int rA = lane & 15, q4 = lane >> 4;
  f32x4 acc[4][4];
#pragma unroll
  for (int i = 0; i < 4; i++)
#pragma unroll
    for (int j = 0; j < 4; j++) acc[i][j] = (f32x4){0.f, 0.f, 0.f, 0.f};

  int arow[4], brow[4];
#pragma unroll
  for (int t = 0; t < 4; ++t) {
    int r = wave * 32 + t * 8 + rr;
    arow[t] = (m0 + r < rows) ? (m0 + r) : (rows - 1);
    brow[t] = (n0 + r < N) ? (n0 + r) : (N - 1);
  }

  for (int k0 = 0; k0 < KE; k0 += 64) {
    __syncthreads();
#pragma unroll
    for (int t = 0; t < 4; ++t) {
      int c = wave * 4 + t;
      g2l16(A + (size_t)arow[t] * KE + k0 + srcOff, &As[c * 512]);
      g2l16(Bb + (size_t)brow[t] * KE + k0 + srcOff, &Bs[c * 512]);
    }
    __syncthreads();
#pragma unroll
    for (int kk = 0; kk < 2; ++kk) {
      bf16x8 af[4], bfr[4];
#pragma unroll
      for (int i = 0; i < 4; i++) {
        int row = mw + i * 16 + rA;
        af[i] = *(const bf16x8*)&As[row * 64 + ((((kk << 2) + q4) ^ (row & 7)) << 3)];
      }
#pragma unroll
      for (int j = 0; j < 4; j++) {
        int row = nw + j * 16 + rA;
        bfr[j] = *(const bf16x8*)&Bs[row * 64 + ((((kk << 2) + q4) ^ (row & 7)) << 3)];
      }
#pragma unroll
      for (int i = 0; i < 4; i++)
#pragma unroll
        for (int j = 0; j < 4; j++)
          acc[i][j] = __builtin_amdgcn_mfma_f32_16x16x32_bf16(af[i], bfr[j], acc[i][j], 0, 0, 0);
    }
  }

  int vj[4];
  float b1j[4];
#pragma unroll
  for (int j = 0; j < 4; j++) {
    int n = n0 + nw + j * 16 + rA;
    if (n >= N) n = N - 1;
    vj[j] = n / H;
    b1j[j] = b1[n];
  }
  // 128-row tile lies inside one batch when T%128==0 -> hoist b and wv factors.
  int bBase = ((T & 127) == 0) ? (int)((moff + m0) / T) : -1;
  float wfac[4];
#pragma unroll
  for (int j = 0; j < 4; j++)
    wfac[j] = (bBase >= 0) ? wv[bBase * V + vj[j]] : 0.f;
#pragma unroll
  for (int i = 0; i < 4; i++) {
#pragma unroll
    for (int r = 0; r < 4; r++) {
      int m = m0 + mw + i * 16 + q4 * 4 + r;
      if (m >= rows) continue;
      long gm = moff + m;
      int bb = (bBase >= 0) ? bBase : (int)(gm / T);
#pragma unroll
      for (int j = 0; j < 4; j++) {
        int n = n0 + nw + j * 16 + rA;
        if (n >= N) continue;
        float val = gelu_fast(acc[i][j][r] + b1j[j]);
        float wf = (bBase >= 0) ? wfac[j] : wv[bb * V + vj[j]];
        hmid[(size_t)m * N + n] = (bf16)(val * wf);
      }
    }
  }
}

// ---------- MFMA GEMM2 (K-split, partial buffers, no atomics): part[z] = hmid·W2b^T ----------
__global__ __launch_bounds__(256, 2) void gemm2_mfma(
    const bf16* __restrict__ A, const bf16* __restrict__ W2b, float* __restrict__ part,
    long partStride, int rows, int H, int K, int kchunk) {
  __shared__ __align__(16) bf16 As[128 * 64];
  __shared__ __align__(16) bf16 Bs[128 * 64];
  const int wave = threadIdx.x >> 6, lane = threadIdx.x & 63;
  // XCD-chunked remap: XCD k owns m-chunk-rows (A panels read once per XCD).
  int bx = blockIdx.x, by = blockIdx.y;
  if (gridDim.x == 8 && (gridDim.y & 31) == 0) {
    int f = by * 8 + bx;
    int xcd = f & 7, q = f >> 3;
    int cs = q >> 5, t = q & 31;
    bx = t & 7;
    by = (xcd + (cs << 3)) * 4 + (t >> 3);
  }
  const int m0 = by * 128, n0 = bx * 128;
  const int mw = (wave >> 1) * 64, nw = (wave & 1) * 64;
  const int rr = lane >> 3;
  const int srcOff = ((lane & 7) ^ rr) << 3;
  const int rA = lane & 15, q4 = lane >> 4;
  int kz0 = blockIdx.z * kchunk;
  int kz1 = kz0 + kchunk; if (kz1 > K) kz1 = K;
  if (kz0 >= K) return;
  f32x4 acc[4][4];
#pragma unroll
  for (int i = 0; i < 4; i++)
#pragma unroll
    for (int j = 0; j < 4; j++) acc[i][j] = (f32x4){0.f, 0.f, 0.f, 0.f};

  int arow[4], brow[4];
#pragma unroll
  for (int t = 0; t < 4; ++t) {
    int r = wave * 32 + t * 8 + rr;
    arow[t] = (m0 + r < rows) ? (m0 + r) : (rows - 1);
    brow[t] = (n0 + r < H) ? (n0 + r) : (H - 1);
  }

  int kv = kz0 / H, kh = kz0 % H;
  for (int k0 = kz0; k0 < kz1; k0 += 64) {
    const bf16* Bk = W2b + (size_t)kv * H * H + kh;
    __syncthreads();
#pragma unroll
    for (int t = 0; t < 4; ++t) {
      int c = wave * 4 + t;
      g2l16(A + (size_t)arow[t] * K + k0 + srcOff, &As[c * 512]);
      g2l16(Bk + (size_t)brow[t] * H + srcOff, &Bs[c * 512]);
    }
    __syncthreads();
#pragma unroll
    for (int kk = 0; kk < 2; ++kk) {
      bf16x8 af[4], bfr[4];
#pragma unroll
      for (int i = 0; i < 4; i++) {
        int row = mw + i * 16 + rA;
        af[i] = *(const bf16x8*)&As[row * 64 + ((((kk << 2) + q4) ^ (row & 7)) << 3)];
      }
#pragma unroll
      for (int j = 0; j < 4; j++) {
        int row = nw + j * 16 + rA;
        bfr[j] = *(const bf16x8*)&Bs[row * 64 + ((((kk << 2) + q4) ^ (row & 7)) << 3)];
      }
#pragma unroll
      for (int i = 0; i < 4; i++)
#pragma unroll
        for (int j = 0; j < 4; j++)
          acc[i][j] = __builtin_amdgcn_mfma_f32_16x16x32_bf16(af[i], bfr[j], acc[i][j], 0, 0, 0);
    }
    kh += 64;
    if (kh >= H) { kh = 0; kv++; }
  }

  float* pz = part + (size_t)blockIdx.z * partStride;
#pragma unroll
  for (int i = 0; i < 4; i++) {
#pragma unroll
    for (int r = 0; r < 4; r++) {
      int m = m0 + mw + i * 16 + q4 * 4 + r;
      if (m >= rows) continue;
#pragma unroll
      for (int j = 0; j < 4; j++) {
        int n = n0 + nw + j * 16 + rA;
        if (n >= H) continue;
        pz[(size_t)m * H + n] = acc[i][j][r];
      }
    }
  }
}

// ---------- out[gm] = wb2[b] + sum_z part[z][m]  (fused seed + K-split reduce) ----------
__global__ void k_red(const float* __restrict__ part, const float* __restrict__ wb2,
                      float* __restrict__ outY, long moff, int rows, long partStride,
                      int H, int T, int ZS) {
  int wave = threadIdx.x >> 6, lane = threadIdx.x & 63;
  long m = (long)blockIdx.x * 4 + wave;
  if (m >= rows) return;
  long gm = moff + m;
  int b = (int)(gm / T);
  const float* w = wb2 + (size_t)b * H;
  float* d = outY + (size_t)gm * H;
  for (int e = lane * 4; e + 4 <= H; e += 256) {
    float4 s = *(const float4*)(w + e);
    for (int z = 0; z < ZS; z++) {
      float4 p = *(const float4*)(part + (size_t)z * partStride + (size_t)m * H + e);
      s.x += p.x; s.y += p.y; s.z += p.z; s.w += p.w;
    }
    *(float4*)(d + e) = s;
  }
}

extern "C" void kernel_launch(void* const* d_in, const int* in_sizes, int n_in,
                              void* d_out, int out_size, void* d_ws, size_t ws_size,
                              hipStream_t stream) {
  const float* x      = (const float*)d_in[0];
  const float* W_tt   = (const float*)d_in[1];
  const float* b_tt   = (const float*)d_in[2];
  const float* W_pol  = (const float*)d_in[3];
  const float* b_pol  = (const float*)d_in[4];
  const float* W_c2h  = (const float*)d_in[5];
  const float* b_c2h  = (const float*)d_in[6];
  const float* W_hh   = (const float*)d_in[8];
  const float* b_ih   = (const float*)d_in[9];
  const float* b_hh   = (const float*)d_in[10];
  const float* W_proj = (const float*)d_in[11];
  const float* b_proj = (const float*)d_in[12];
  const float* W1     = (const float*)d_in[13];
  const float* b1     = (const float*)d_in[14];
  const float* W2     = (const float*)d_in[15];
  const float* b2     = (const float*)d_in[16];
  float* out = (float*)d_out;
  char* ws = (char*)d_ws;

  const int C1 = in_sizes[2];
  const int C2 = in_sizes[4];
  const int H  = in_sizes[1] / C1;
  const int DC = C1 + C2;
  const int DIN = H + DC;
  const int V  = in_sizes[12];
  const long BT = (long)in_sizes[0] / H;
  long R = (long)out_size - BT * (long)(H + DC);
  int B = 0, L = 0;
  for (int Lc = 1; Lc <= 32; ++Lc) {
    long den = (long)Lc * V + H;
    if (R % den == 0) {
      long Bc = R / den;
      if (Bc >= 1 && BT % Bc == 0) {
        if (B == 0 || Lc == 4) { B = (int)Bc; L = Lc; }
        if (Lc == 4) break;
      }
    }
  }
  if (B == 0) { B = 8; L = 4; }
  const int T = (int)(BT / B);
  const long N2 = (long)V * H;
  const int KE = H + 64;          // BK=64-aligned K-extension (zero padded)
  const int ZS = 4;

  size_t o = 0;
  auto alloc = [&](size_t bytes) { size_t r = o; o = (o + bytes + 255) & ~(size_t)255; return r; };
  float* feats  = (float*)(ws + alloc((size_t)BT * DC * 4));
  size_t off_pooled = alloc((size_t)B * H * 4);
  float* pooled = (float*)(ws + off_pooled);
  float* fsum   = (float*)(ws + alloc((size_t)B * DC * 4));
  float* hbuf   = (float*)(ws + alloc((size_t)2 * B * H * 4));
  float* hs     = (float*)(ws + alloc((size_t)L * B * H * 4));
  float* logits = (float*)(ws + alloc((size_t)B * L * V * 4));
  float* wv     = (float*)(ws + alloc((size_t)B * V * 4));
  float* wb2    = (float*)(ws + alloc((size_t)B * H * 4));
  bf16* xbE  = (bf16*)(ws + alloc((size_t)BT * KE * 2));
  bf16* W1bE = (bf16*)(ws + alloc((size_t)N2 * KE * 2));
  bf16* W2b  = (bf16*)(ws + alloc((size_t)N2 * H * 2));
  size_t off_hmid = alloc(0);
  // per-row footprint: hmid (N2 bf16) + ZS f32 partials (H each)
  long rowBytes = N2 * 2 + (long)ZS * H * 4;
  long avail = (long)ws_size - (long)off_hmid;
  long Mc = ((avail / rowBytes) / 128) * 128;
  long bt128 = ((BT + 127) / 128) * 128;
  if (Mc > bt128) Mc = bt128;
  if (Mc < 128) Mc = 128;
  bf16* hmid = (bf16*)(ws + off_hmid);
  float* part = (float*)(ws + off_hmid + (size_t)Mc * N2 * 2);
  long partStride = Mc * (long)H;

  float* out_y    = out;
  float* out_log  = out_y + (size_t)BT * H;
  float* out_tt   = out_log + (size_t)B * L * V;
  float* out_pol  = out_tt + (size_t)BT * C1;
  float* out_pool = out_pol + (size_t)BT * C2;

  hipMemsetAsync(ws + off_pooled, 0, (size_t)B * H * 4, stream);

  // weight prep (W1bE + W2b) in one kernel
  int nW1 = (int)((N2 + 3) / 4);
  int nCvt = 1024;
  k_prep<<<nW1 + nCvt, 256, 0, stream>>>(W1, W1bE, W2, W2b, H, DIN, KE, DC, N2,
                                         nW1, (long)nCvt * 256);
  // front: feats/tt/pol + xbE in one x pass
  if (DC == 8 && (H & 1023) == 0) {
    k_front_t<8><<<(int)((BT + 3) / 4), 256, 0, stream>>>(x, W_tt, b_tt, W_pol, b_pol,
                                                          out_tt, out_pol, feats, xbE,
                                                          H, KE, BT, C1, C2);
  } else {
    k_feats_g<<<(int)((BT + 3) / 4), 256, 0, stream>>>(x, W_tt, b_tt, W_pol, b_pol,
                                                       out_tt, out_pol, feats,
                                                       H, T, (int)BT, C1, C2);
    k_xext<<<(int)((BT + 3) / 4), 256, 0, stream>>>(x, feats, xbE, H, KE, DC, BT);
  }
  // pooled + fsum in one kernel
  int hBlocks = (H + 255) / 256;
  int poolBlocks = B * hBlocks * 8;
  int fsumBlocks = (B * DC + 3) / 4;
  k_stats<<<poolBlocks + fsumBlocks, 256, 0, stream>>>(x, pooled, feats, fsum,
                                                       H, T, 8, DC, B * DC, poolBlocks);
  k_ctx_h0<<<(B * H + 3) / 4, 256, 0, stream>>>(W_c2h, b_c2h, pooled, fsum,
                                                hbuf, out_pool, H, DIN, B, DC);
  float* hA = hbuf;
  float* hB = hbuf + (size_t)B * H;
  for (int l = 0; l < L; ++l) {
    k_gru<<<(B * H + 3) / 4, 256, 0, stream>>>((l & 1) ? hB : hA, W_hh, b_ih, b_hh,
                                               (l & 1) ? hA : hB, hs + (size_t)l * B * H,
                                               H, B);
  }
  k_logits<<<(B * L * V + 3) / 4, 256, 0, stream>>>(hs, W_proj, b_proj, logits,
                                                    out_log, H, B, L, V);
  k_wmix<<<1, 256, 0, stream>>>(logits, b2, wv, wb2, B, L, V, H);

  int kchunk = (int)((((N2 / ZS) + 63) / 64) * 64);
  for (long moff = 0; moff < BT; moff += Mc) {
    int rows = (int)(((BT - moff) < Mc) ? (BT - moff) : Mc);
    dim3 g1((unsigned)((N2 + 127) / 128), (unsigned)((rows + 127) / 128));
    dim3 g2((unsigned)((H + 127) / 128), (unsigned)((rows + 127) / 128), ZS);
    gemm1_mfma<<<g1, 256, 0, stream>>>(xbE + (size_t)moff * KE, W1bE, hmid, b1, wv,
                                       rows, moff, KE, H, (int)N2, T, V);
    gemm2_mfma<<<g2, 256, 0, stream>>>(hmid, W2b, part, partStride,
                                       rows, H, (int)N2, kchunk);
    k_red<<<(int)((rows + 3) / 4), 256, 0, stream>>>(part, wb2, out_y, moff, rows,
                                                     partStride, H, T, ZS);
  }
}